// Round 1
// baseline (223.674 us; speedup 1.0000x reference)
//
#include <hip/hip_runtime.h>

// out[r][c] = x[r][c] * diag[c]
// x: 16384 x 2048 fp32, diag: 2048 fp32. Memory-bound broadcast multiply.
// One thread per float4 (16 B/lane coalescing sweet spot). Row width is
// 512 float4s (2048 floats), power of two -> diag index is (i & 511).
__global__ __launch_bounds__(256) void DiagonalDense_kernel(
    const float4* __restrict__ x,
    const float4* __restrict__ diag,
    float4* __restrict__ out,
    int n4) {
    int i = blockIdx.x * blockDim.x + threadIdx.x;
    if (i < n4) {
        float4 xv = x[i];
        float4 dv = diag[i & 511];   // 2048 cols / 4 = 512 float4 per row
        float4 ov;
        ov.x = xv.x * dv.x;
        ov.y = xv.y * dv.y;
        ov.z = xv.z * dv.z;
        ov.w = xv.w * dv.w;
        out[i] = ov;
    }
}

extern "C" void kernel_launch(void* const* d_in, const int* in_sizes, int n_in,
                              void* d_out, int out_size, void* d_ws, size_t ws_size,
                              hipStream_t stream) {
    const float4* x    = (const float4*)d_in[0];   // 16384*2048 fp32
    const float4* diag = (const float4*)d_in[1];   // 2048 fp32
    float4* out        = (float4*)d_out;

    const int n  = out_size;       // 33,554,432
    const int n4 = n / 4;          // 8,388,608 (exactly divisible)
    const int block = 256;
    const int grid  = (n4 + block - 1) / block;   // 32768 blocks

    DiagonalDense_kernel<<<grid, block, 0, stream>>>(x, diag, out, n4);
}